// Round 1
// baseline (424.352 us; speedup 1.0000x reference)
//
#include <hip/hip_runtime.h>

// out[b, i*16+k, h, w] = x[b, i*16+k, h, w]
//   + sum_j ( sum_g rd[g](h,w) * Up(sigmoid(depth))[b, g*256 + i*64 + j*16 + k, h, w] ) * x[b, j*16+k, h, w]
// Up = 2x bilinear, half-pixel centers, edge-clamped (== jax.image.resize renormalized).
// rd[g] = max(1 - |g - depth_ori*3|, 0)

__device__ __forceinline__ float sigmoid_fast(float v) {
    // 1 / (1 + 2^(-v * log2 e))
    float e = __builtin_amdgcn_exp2f(v * -1.44269504088896340736f);
    return __builtin_amdgcn_rcpf(1.0f + e);
}

__global__ __launch_bounds__(256) void seblock_kernel(
    const float* __restrict__ x,
    const float* __restrict__ depth,
    const float* __restrict__ dori,
    float* __restrict__ out)
{
    const int t  = blockIdx.x * 256 + threadIdx.x;
    const int n  = t & 63;          // w input-tile index (output cols 2n, 2n+1)
    const int m  = (t >> 6) & 63;   // h input-tile index (output rows 2m, 2m+1)
    const int oc = (t >> 12) & 63;  // output channel
    const int b  = t >> 18;         // batch
    const int i  = oc >> 4;
    const int k  = oc & 15;

    const int h0 = m << 1, w0 = n << 1;

    // ---- depth_ori (b,1,128,128): 2x2 pixels, float2 per row ----
    const float* dop = dori + ((size_t)b * 128 + h0) * 128 + w0;
    const float2 q0 = *reinterpret_cast<const float2*>(dop);
    const float2 q1 = *reinterpret_cast<const float2*>(dop + 128);
    const float z[4] = { q0.x * 3.0f, q0.y * 3.0f, q1.x * 3.0f, q1.y * 3.0f };

    // ---- x (b,64,128,128): channels j*16+k, 2x2 pixels each ----
    float xs[4][4];
    #pragma unroll
    for (int j = 0; j < 4; ++j) {
        const float* xp = x + (((size_t)b * 64 + (j * 16 + k)) * 128 + h0) * 128 + w0;
        const float2 a = *reinterpret_cast<const float2*>(xp);
        const float2 c = *reinterpret_cast<const float2*>(xp + 128);
        xs[j][0] = a.x; xs[j][1] = a.y; xs[j][2] = c.x; xs[j][3] = c.y;
    }

    // identity term: out = x[i*16+k] + ...
    float acc[4] = { xs[i][0], xs[i][1], xs[i][2], xs[i][3] };

    // clamped 3x3 tap rows/cols in the 64x64 input grid
    const int rm = (m > 0)  ? m - 1 : 0;
    const int rp = (m < 63) ? m + 1 : 63;
    const int cm = (n > 0)  ? n - 1 : 0;
    const int cp = (n < 63) ? n + 1 : 63;

    #pragma unroll
    for (int g = 0; g < 3; ++g) {
        float rdw[4];
        #pragma unroll
        for (int p = 0; p < 4; ++p)
            rdw[p] = fmaxf(1.0f - fabsf((float)g - z[p]), 0.0f);

        #pragma unroll
        for (int j = 0; j < 4; ++j) {
            const int ch = g * 256 + i * 64 + j * 16 + k;
            const float* dp = depth + ((size_t)b * 768 + ch) * 4096;
            const float* r0 = dp + rm * 64;
            const float* r1 = dp + m  * 64;
            const float* r2 = dp + rp * 64;

            const float s00 = sigmoid_fast(r0[cm]), s01 = sigmoid_fast(r0[n]), s02 = sigmoid_fast(r0[cp]);
            const float s10 = sigmoid_fast(r1[cm]), s11 = sigmoid_fast(r1[n]), s12 = sigmoid_fast(r1[cp]);
            const float s20 = sigmoid_fast(r2[cm]), s21 = sigmoid_fast(r2[n]), s22 = sigmoid_fast(r2[cp]);

            // vertical mixes: out-row 2m uses (0.25,0.75) on rows (m-1,m); 2m+1 uses (0.75,0.25) on (m,m+1)
            const float vt0 = 0.25f * s00 + 0.75f * s10;
            const float vt1 = 0.25f * s01 + 0.75f * s11;
            const float vt2 = 0.25f * s02 + 0.75f * s12;
            const float vb0 = 0.75f * s10 + 0.25f * s20;
            const float vb1 = 0.75f * s11 + 0.25f * s21;
            const float vb2 = 0.75f * s12 + 0.25f * s22;

            // horizontal mixes: out-col 2n = 0.25*col(n-1)+0.75*col(n); 2n+1 = 0.75*col(n)+0.25*col(n+1)
            const float u0 = 0.25f * vt0 + 0.75f * vt1;  // (2m,   2n  )
            const float u1 = 0.75f * vt1 + 0.25f * vt2;  // (2m,   2n+1)
            const float u2 = 0.25f * vb0 + 0.75f * vb1;  // (2m+1, 2n  )
            const float u3 = 0.75f * vb1 + 0.25f * vb2;  // (2m+1, 2n+1)

            acc[0] = fmaf(rdw[0] * u0, xs[j][0], acc[0]);
            acc[1] = fmaf(rdw[1] * u1, xs[j][1], acc[1]);
            acc[2] = fmaf(rdw[2] * u2, xs[j][2], acc[2]);
            acc[3] = fmaf(rdw[3] * u3, xs[j][3], acc[3]);
        }
    }

    float* op = out + (((size_t)b * 64 + oc) * 128 + h0) * 128 + w0;
    *reinterpret_cast<float2*>(op)       = make_float2(acc[0], acc[1]);
    *reinterpret_cast<float2*>(op + 128) = make_float2(acc[2], acc[3]);
}

extern "C" void kernel_launch(void* const* d_in, const int* in_sizes, int n_in,
                              void* d_out, int out_size, void* d_ws, size_t ws_size,
                              hipStream_t stream) {
    const float* x     = (const float*)d_in[0];
    const float* depth = (const float*)d_in[1];
    const float* dori  = (const float*)d_in[2];
    float* out = (float*)d_out;

    // 8 b * 64 oc * 64 m * 64 n = 2,097,152 threads -> 8192 blocks of 256
    seblock_kernel<<<8192, 256, 0, stream>>>(x, depth, dori, out);
}

// Round 2
// 183.745 us; speedup vs baseline: 2.3095x; 2.3095x over previous
//
#include <hip/hip_runtime.h>

// out[b, i*16+k, h, w] = x[b, i*16+k, h, w]
//   + sum_j ( sum_g rd[g](h,w) * Up(sigmoid(depth))[b, g*256 + i*64 + j*16 + k, h, w] ) * x[b, j*16+k, h, w]
// Up = 2x bilinear, half-pixel centers, edge-clamped (== jax.image.resize renormalized).
// rd[g] = max(1 - |g - depth_ori*3|, 0)
//
// Wave layout: lane == n (input column), so horizontal +-1 taps are neighbor
// lanes; __shfl_up/__shfl_down edge behavior (lane keeps own value) == column clamp.

__device__ __forceinline__ float sigmoid_fast(float v) {
    float e = __builtin_amdgcn_exp2f(v * -1.44269504088896340736f);
    return __builtin_amdgcn_rcpf(1.0f + e);
}

__global__ __launch_bounds__(256) void seblock_kernel(
    const float* __restrict__ x,
    const float* __restrict__ depth,
    const float* __restrict__ dori,
    float* __restrict__ out)
{
    const int t  = blockIdx.x * 256 + threadIdx.x;
    const int n  = t & 63;          // w input-tile index == lane (output cols 2n, 2n+1)
    const int m  = (t >> 6) & 63;   // h input-tile index (output rows 2m, 2m+1)
    const int oc = (t >> 12) & 63;  // output channel
    const int b  = t >> 18;         // batch
    const int i  = oc >> 4;
    const int k  = oc & 15;

    const int h0 = m << 1, w0 = n << 1;

    // ---- batched depth loads: all 36 taps (3 rows x 12 channels) up-front ----
    const int rm = (m > 0)  ? m - 1 : 0;
    const int rp = (m < 63) ? m + 1 : 63;

    float dv[3][4][3];  // [g][j][row]  -- fully unrolled => static indexing => VGPRs
    #pragma unroll
    for (int g = 0; g < 3; ++g) {
        #pragma unroll
        for (int j = 0; j < 4; ++j) {
            const float* dp = depth + ((size_t)b * 768 + (g * 256 + i * 64 + j * 16 + k)) * 4096 + n;
            dv[g][j][0] = dp[rm * 64];
            dv[g][j][1] = dp[m  * 64];
            dv[g][j][2] = dp[rp * 64];
        }
    }

    // ---- depth_ori (b,1,128,128): 2x2 pixels ----
    const float* dop = dori + ((size_t)b * 128 + h0) * 128 + w0;
    const float2 q0 = *reinterpret_cast<const float2*>(dop);
    const float2 q1 = *reinterpret_cast<const float2*>(dop + 128);
    const float z[4] = { q0.x * 3.0f, q0.y * 3.0f, q1.x * 3.0f, q1.y * 3.0f };

    // ---- x (b,64,128,128): channels j*16+k, 2x2 pixels each ----
    float xs[4][4];
    #pragma unroll
    for (int j = 0; j < 4; ++j) {
        const float* xp = x + (((size_t)b * 64 + (j * 16 + k)) * 128 + h0) * 128 + w0;
        const float2 a = *reinterpret_cast<const float2*>(xp);
        const float2 c = *reinterpret_cast<const float2*>(xp + 128);
        xs[j][0] = a.x; xs[j][1] = a.y; xs[j][2] = c.x; xs[j][3] = c.y;
    }

    float acc[4] = { xs[i][0], xs[i][1], xs[i][2], xs[i][3] };

    #pragma unroll
    for (int g = 0; g < 3; ++g) {
        float rdw[4];
        #pragma unroll
        for (int p = 0; p < 4; ++p)
            rdw[p] = fmaxf(1.0f - fabsf((float)g - z[p]), 0.0f);

        #pragma unroll
        for (int j = 0; j < 4; ++j) {
            const float a0 = sigmoid_fast(dv[g][j][0]);
            const float a1 = sigmoid_fast(dv[g][j][1]);
            const float a2 = sigmoid_fast(dv[g][j][2]);

            // vertical mixes at this column:
            // out-row 2m   uses (0.25, 0.75) on input rows (m-1, m)
            // out-row 2m+1 uses (0.75, 0.25) on input rows (m, m+1)
            const float vt = fmaf(0.25f, a0, 0.75f * a1);
            const float vb = fmaf(0.25f, a2, 0.75f * a1);

            // horizontal neighbors via wave shuffle (lane == n); edge lanes keep
            // their own value == column clamp.
            const float vtm = __shfl_up(vt, 1);
            const float vtp = __shfl_down(vt, 1);
            const float vbm = __shfl_up(vb, 1);
            const float vbp = __shfl_down(vb, 1);

            const float u0 = fmaf(0.25f, vtm, 0.75f * vt);  // (2m,   2n  )
            const float u1 = fmaf(0.25f, vtp, 0.75f * vt);  // (2m,   2n+1)
            const float u2 = fmaf(0.25f, vbm, 0.75f * vb);  // (2m+1, 2n  )
            const float u3 = fmaf(0.25f, vbp, 0.75f * vb);  // (2m+1, 2n+1)

            acc[0] = fmaf(rdw[0] * u0, xs[j][0], acc[0]);
            acc[1] = fmaf(rdw[1] * u1, xs[j][1], acc[1]);
            acc[2] = fmaf(rdw[2] * u2, xs[j][2], acc[2]);
            acc[3] = fmaf(rdw[3] * u3, xs[j][3], acc[3]);
        }
    }

    float* op = out + (((size_t)b * 64 + oc) * 128 + h0) * 128 + w0;
    *reinterpret_cast<float2*>(op)       = make_float2(acc[0], acc[1]);
    *reinterpret_cast<float2*>(op + 128) = make_float2(acc[2], acc[3]);
}

extern "C" void kernel_launch(void* const* d_in, const int* in_sizes, int n_in,
                              void* d_out, int out_size, void* d_ws, size_t ws_size,
                              hipStream_t stream) {
    const float* x     = (const float*)d_in[0];
    const float* depth = (const float*)d_in[1];
    const float* dori  = (const float*)d_in[2];
    float* out = (float*)d_out;

    // 8 b * 64 oc * 64 m * 64 n = 2,097,152 threads -> 8192 blocks of 256
    seblock_kernel<<<8192, 256, 0, stream>>>(x, depth, dori, out);
}